// Round 4
// baseline (402.956 us; speedup 1.0000x reference)
//
#include <hip/hip_runtime.h>

// Problem constants (match reference)
constexpr int NB = 16384;   // B
constexpr int NK = 50;      // K
constexpr int NH = 64;      // H
constexpr float REG = 0.01f;
constexpr int G  = 2;       // b's per wave
constexpr int NGRP = (NK + 3) / 4;  // 13 row-groups of 4 rows (quarter-wave each)

// acc[0] = sum (pred-target)^2 over B*K
// acc[1] = sum ||ue||          over B
// acc[2] = sum ||ie||          over B*K

// Wave = one b at a time; quarter-wave (16 lanes) = one item row.
// One global_load_dwordx4 moves 4 complete 256B rows (8 contiguous cache lines)
// -> ~104 L1 line-transactions per b vs ~800 for the divergent layout.
__global__ __launch_bounds__(256) void mf_main(
    const float* __restrict__ user_weight,   // [NU, H]
    const float* __restrict__ item_weight,   // [NI, H]
    const float* __restrict__ user_bias,     // [NU, 1]
    const float* __restrict__ item_bias,     // [NI, 1]
    const float* __restrict__ gbias,         // [1]
    const float* __restrict__ target,        // [B, K]
    const int*   __restrict__ user,          // [B]
    const int*   __restrict__ item,          // [B, K]
    float* __restrict__ out,                 // [B*K + 1]
    float* __restrict__ acc)                 // [3] zeroed
{
    const int tid  = threadIdx.x;
    const int wave = tid >> 6;
    const int lane = tid & 63;
    const int q    = lane >> 4;   // quarter: which row within a group of 4
    const int l16  = lane & 15;   // float4 position within the 256B row
    const bool lk  = (lane < NK);
    const int lcl  = lk ? lane : 0;

    __shared__ float s_red[3][4];

    const float gb = gbias[0];

    int b = (blockIdx.x * 4 + wave) * G;

    // prologue: per-b vectors for g=0 (coalesced, lane<50)
    int   u    = user[b];
    int   kidx = item[b * NK + lcl];
    float tgt  = target[b * NK + lcl];

    float mse_acc = 0.f, ien_acc = 0.f, uen_acc = 0.f;

    #pragma unroll
    for (int g = 0; g < G; ++g) {
        // ---- per-b scalar/vector loads ----
        const float ubv = user_bias[u];
        const float4 uw4 = *reinterpret_cast<const float4*>(user_weight + (size_t)u * NH + l16 * 4);
        const float ibv = lk ? item_bias[kidx] : 0.f;   // 50-lane gather (~50 tx)

        // ---- issue all 13 row-group loads (4 rows / instruction, coalesced) ----
        float4 r[NGRP];
        #pragma unroll
        for (int gr = 0; gr < NGRP; ++gr) {
            int k = gr * 4 + q;
            int kk = (k < NK) ? k : (NK - 1);
            const int it = __shfl(kidx, kk);            // broadcast row index to quarter
            r[gr] = *reinterpret_cast<const float4*>(item_weight + (size_t)it * NH + l16 * 4);
        }

        // ---- prefetch next b's indices while rows are in flight ----
        int nu = u, nkidx = kidx; float ntgt = tgt;
        if (g + 1 < G) {
            nu    = user[b + 1];
            nkidx = item[(b + 1) * NK + lcl];
            ntgt  = target[(b + 1) * NK + lcl];
        }

        // ---- user embedding segment (registers; identical across quarters) ----
        const float4 ue4 = make_float4(uw4.x + ubv, uw4.y + ubv, uw4.z + ubv, uw4.w + ubv);
        float us = ue4.x * ue4.x + ue4.y * ue4.y + ue4.z * ue4.z + ue4.w * ue4.w;
        #pragma unroll
        for (int off = 8; off > 0; off >>= 1) us += __shfl_down(us, off, 16);
        if (lane == 0) uen_acc += sqrtf(us);

        // ---- consume rows ----
        #pragma unroll
        for (int gr = 0; gr < NGRP; ++gr) {
            const int k  = gr * 4 + q;
            const int kk = (k < NK) ? k : (NK - 1);
            const float ib = __shfl(ibv, kk);
            const float tg = __shfl(tgt, kk);
            const float iex = r[gr].x + ib;
            const float iey = r[gr].y + ib;
            const float iez = r[gr].z + ib;
            const float iew = r[gr].w + ib;
            float pdot = iex * ue4.x + iey * ue4.y + iez * ue4.z + iew * ue4.w;
            float psq  = iex * iex   + iey * iey   + iez * iez   + iew * iew;
            #pragma unroll
            for (int off = 8; off > 0; off >>= 1) {
                pdot += __shfl_down(pdot, off, 16);
                psq  += __shfl_down(psq,  off, 16);
            }
            if (l16 == 0 && k < NK) {                   // lanes 0,16,32,48: 4 consecutive dwords
                const float pred = pdot + gb;
                out[b * NK + k] = pred;
                const float d = pred - tg;
                mse_acc += d * d;
                ien_acc += sqrtf(psq);
            }
        }

        b += 1; u = nu; kidx = nkidx; tgt = ntgt;
    }

    // ---- wave reduction: partials live on lanes {0,16,32,48} ----
    mse_acc += __shfl_down(mse_acc, 32);
    mse_acc += __shfl_down(mse_acc, 16);
    ien_acc += __shfl_down(ien_acc, 32);
    ien_acc += __shfl_down(ien_acc, 16);

    if (lane == 0) {
        s_red[0][wave] = mse_acc;
        s_red[1][wave] = uen_acc;
        s_red[2][wave] = ien_acc;
    }
    __syncthreads();
    if (tid == 0) {
        atomicAdd(&acc[0], s_red[0][0] + s_red[0][1] + s_red[0][2] + s_red[0][3]);
        atomicAdd(&acc[1], s_red[1][0] + s_red[1][1] + s_red[1][2] + s_red[1][3]);
        atomicAdd(&acc[2], s_red[2][0] + s_red[2][1] + s_red[2][2] + s_red[2][3]);
    }
}

__global__ void mf_finish(const float* __restrict__ acc, float* __restrict__ out)
{
    const float inv_bk = 1.0f / (float)(NB * NK);
    const float mse = acc[0] * inv_bk;
    const float loss = mse + REG * (acc[1] / (float)NB) + REG * (acc[2] * inv_bk);
    out[NB * NK] = loss;
}

extern "C" void kernel_launch(void* const* d_in, const int* in_sizes, int n_in,
                              void* d_out, int out_size, void* d_ws, size_t ws_size,
                              hipStream_t stream) {
    const float* user_weight = (const float*)d_in[0];
    const float* item_weight = (const float*)d_in[1];
    const float* user_bias   = (const float*)d_in[2];
    const float* item_bias   = (const float*)d_in[3];
    const float* gbias       = (const float*)d_in[4];
    const float* target      = (const float*)d_in[5];
    const int*   user        = (const int*)d_in[6];
    const int*   item        = (const int*)d_in[7];
    float* out = (float*)d_out;
    float* acc = (float*)d_ws;

    hipMemsetAsync(acc, 0, 3 * sizeof(float), stream);
    mf_main<<<NB / (4 * G), 256, 0, stream>>>(user_weight, item_weight, user_bias, item_bias,
                                              gbias, target, user, item, out, acc);
    mf_finish<<<1, 1, 0, stream>>>(acc, out);
}

// Round 5
// 376.849 us; speedup vs baseline: 1.0693x; 1.0693x over previous
//
#include <hip/hip_runtime.h>

// Problem constants (match reference)
constexpr int NB = 16384;   // B
constexpr int NK = 50;      // K
constexpr int NH = 64;      // H
constexpr float REG = 0.01f;
constexpr int G  = 4;       // b's per wave

// acc[0] = sum (pred-target)^2 over B*K
// acc[1] = sum ||ue||          over B
// acc[2] = sum ||ie||          over B*K

// R3 structure (lane = one (b,k) pair, dot fully in-lane) with launch_bounds
// relaxed to (256,4): VGPR budget 128 so the full 16-float4 row buffer stays
// live and ALL 16 row loads are outstanding at once (12.8 KB/wave in flight).
// Grid = 1024 blocks = 4 blocks/CU co-resident, no churn, no hot-loop barrier.
__global__ __launch_bounds__(256, 4) void mf_main(
    const float* __restrict__ user_weight,   // [NU, H]
    const float* __restrict__ item_weight,   // [NI, H]
    const float* __restrict__ user_bias,     // [NU, 1]
    const float* __restrict__ item_bias,     // [NI, 1]
    const float* __restrict__ gbias,         // [1]
    const float* __restrict__ target,        // [B, K]
    const int*   __restrict__ user,          // [B]
    const int*   __restrict__ item,          // [B, K]
    float* __restrict__ out,                 // [B*K + 1]
    float* __restrict__ acc)                 // [3] zeroed
{
    const int tid  = threadIdx.x;
    const int wave = tid >> 6;
    const int lane = tid & 63;
    const int kcl  = (lane < NK) ? lane : (NK - 1);  // clamped k (no exec branch)
    const bool active = (lane < NK);

    __shared__ __align__(16) float s_ue[4][NH];      // strictly per-wave slot
    __shared__ float s_red[3][4];

    const float gb = gbias[0];

    int b  = (blockIdx.x * 4 + wave) * G;

    // prologue: everything for g=0
    int   u   = user[b];
    int   it  = item[b * NK + kcl];
    float ubv = user_bias[u];
    float tgt = target[b * NK + kcl];

    float mse_acc = 0.f, ien_acc = 0.f, uen_acc = 0.f;

    #pragma unroll
    for (int g = 0; g < G; ++g) {
        // ---- issue ALL gathers for current b (16 independent dwordx4/lane) ----
        const float ibv = item_bias[it];
        const float uev = user_weight[(size_t)u * NH + lane] + ubv;

        const float4* rowp = reinterpret_cast<const float4*>(item_weight + (size_t)it * NH);
        float4 r[16];
        #pragma unroll
        for (int i = 0; i < 16; ++i) r[i] = rowp[i];

        // ---- prefetch next b's small operands while rows are in flight ----
        int nu = u, nit = it; float nubv = ubv, ntgt = tgt;
        if (g + 1 < G) {
            nu   = user[b + 1];
            nit  = item[(b + 1) * NK + kcl];
            nubv = user_bias[nu];
            ntgt = target[(b + 1) * NK + kcl];
        }

        // ---- user norm + LDS stage (independent of item rows) ----
        s_ue[wave][lane] = uev;                        // own slot: lgkmcnt orders, no barrier
        float us = uev * uev;
        #pragma unroll
        for (int off = 32; off > 0; off >>= 1) us += __shfl_down(us, off);
        if (lane == 0) uen_acc += sqrtf(us);

        // ---- dot against LDS-broadcast ue ----
        const float4* uep = reinterpret_cast<const float4*>(&s_ue[wave][0]);
        float dot = 0.f, sq = 0.f;
        #pragma unroll
        for (int i = 0; i < 16; ++i) {
            const float4 ue4 = uep[i];                 // same addr all lanes -> broadcast
            const float iex = r[i].x + ibv;
            const float iey = r[i].y + ibv;
            const float iez = r[i].z + ibv;
            const float iew = r[i].w + ibv;
            dot += iex * ue4.x + iey * ue4.y + iez * ue4.z + iew * ue4.w;
            sq  += iex * iex   + iey * iey   + iez * iez   + iew * iew;
        }
        const float pred = dot + gb;
        if (active) {
            out[b * NK + lane] = pred;
            const float d = pred - tgt;
            mse_acc += d * d;
            ien_acc += sqrtf(sq);
        }

        b += 1; u = nu; it = nit; ubv = nubv; tgt = ntgt;
    }

    // ---- one wave reduction at the end ----
    #pragma unroll
    for (int off = 32; off > 0; off >>= 1) {
        mse_acc += __shfl_down(mse_acc, off);
        ien_acc += __shfl_down(ien_acc, off);
    }
    if (lane == 0) {
        s_red[0][wave] = mse_acc;
        s_red[1][wave] = uen_acc;
        s_red[2][wave] = ien_acc;
    }
    __syncthreads();
    if (tid == 0) {
        atomicAdd(&acc[0], s_red[0][0] + s_red[0][1] + s_red[0][2] + s_red[0][3]);
        atomicAdd(&acc[1], s_red[1][0] + s_red[1][1] + s_red[1][2] + s_red[1][3]);
        atomicAdd(&acc[2], s_red[2][0] + s_red[2][1] + s_red[2][2] + s_red[2][3]);
    }
}

__global__ void mf_finish(const float* __restrict__ acc, float* __restrict__ out)
{
    const float inv_bk = 1.0f / (float)(NB * NK);
    const float mse = acc[0] * inv_bk;
    const float loss = mse + REG * (acc[1] / (float)NB) + REG * (acc[2] * inv_bk);
    out[NB * NK] = loss;
}

extern "C" void kernel_launch(void* const* d_in, const int* in_sizes, int n_in,
                              void* d_out, int out_size, void* d_ws, size_t ws_size,
                              hipStream_t stream) {
    const float* user_weight = (const float*)d_in[0];
    const float* item_weight = (const float*)d_in[1];
    const float* user_bias   = (const float*)d_in[2];
    const float* item_bias   = (const float*)d_in[3];
    const float* gbias       = (const float*)d_in[4];
    const float* target      = (const float*)d_in[5];
    const int*   user        = (const int*)d_in[6];
    const int*   item        = (const int*)d_in[7];
    float* out = (float*)d_out;
    float* acc = (float*)d_ws;

    hipMemsetAsync(acc, 0, 3 * sizeof(float), stream);
    mf_main<<<NB / (4 * G), 256, 0, stream>>>(user_weight, item_weight, user_bias, item_bias,
                                              gbias, target, user, item, out, acc);
    mf_finish<<<1, 1, 0, stream>>>(acc, out);
}

// Round 6
// 368.390 us; speedup vs baseline: 1.0938x; 1.0230x over previous
//
#include <hip/hip_runtime.h>

// Problem constants (match reference)
constexpr int NB = 16384;   // B
constexpr int NK = 50;      // K
constexpr int NH = 64;      // H
constexpr float REG = 0.01f;
constexpr int G  = 4;       // b's per wave
constexpr int NGRP = 13;    // ceil(NK/4) row-groups (quarter-wave = one row)

// acc[0] = sum (pred-target)^2 over B*K
// acc[1] = sum ||ue||          over B
// acc[2] = sum ||ie||          over B*K
//
// Coalesced gather + LDS transpose + in-lane dot:
//  - 13 quarter-wave dwordx4 loads per b move all 50 rows at ~1 tx/cache line
//    (vs 8 tx/line in the divergent lane-per-row layout).
//  - rows land in per-wave LDS with XOR-swizzled chunk columns (bank-balanced
//    for both the transposed write and the per-lane row read; ue read stays
//    same-address broadcast).
//  - lane k dots row k fully in-lane: no per-k shuffle reductions.
//  - no barriers in the hot loop (wave-private LDS slots, DS is wave-ordered).
__global__ __launch_bounds__(256, 3) void mf_main(
    const float* __restrict__ user_weight,   // [NU, H]
    const float* __restrict__ item_weight,   // [NI, H]
    const float* __restrict__ user_bias,     // [NU, 1]
    const float* __restrict__ item_bias,     // [NI, 1]
    const float* __restrict__ gbias,         // [1]
    const float* __restrict__ target,        // [B, K]
    const int*   __restrict__ user,          // [B]
    const int*   __restrict__ item,          // [B, K]
    float* __restrict__ out,                 // [B*K + 1]
    float* __restrict__ acc)                 // [3] zeroed
{
    const int tid  = threadIdx.x;
    const int wave = tid >> 6;
    const int lane = tid & 63;
    const int q    = lane >> 4;   // quarter id: row within a group of 4
    const int l16  = lane & 15;   // float4 chunk within a 256B row
    const bool active = (lane < NK);
    const int kcl  = active ? lane : (NK - 1);

    __shared__ __align__(16) float s_it[4][NK * NH];  // 51.2 KB: per-wave row staging
    __shared__ __align__(16) float s_ue[4][NH];
    __shared__ float s_red[3][4];

    float* __restrict__ sit = s_it[wave];
    float* __restrict__ sue = s_ue[wave];

    const float gb = gbias[0];

    int b = (blockIdx.x * 4 + wave) * G;

    // ---- prologue: all operands for g=0 ----
    int   u    = user[b];
    int   kidx = item[b * NK + kcl];
    float ubv  = user_bias[u];
    float tgt  = target[b * NK + kcl];
    float ibv  = item_bias[kidx];                         // lane k's own row bias
    float uev  = user_weight[(size_t)u * NH + lane] + ubv;

    float4 r[NGRP];
    #pragma unroll
    for (int gr = 0; gr < NGRP; ++gr) {
        const int k  = gr * 4 + q;
        const int kk = (k < NK) ? k : (NK - 1);
        const int it = __shfl(kidx, kk);                  // broadcast row index to quarter
        r[gr] = *reinterpret_cast<const float4*>(item_weight + (size_t)it * NH + l16 * 4);
    }

    float mse_acc = 0.f, ien_acc = 0.f, uen_acc = 0.f;

    #pragma unroll
    for (int g = 0; g < G; ++g) {
        // ---- stage rows -> LDS, XOR-swizzled chunk column ----
        #pragma unroll
        for (int gr = 0; gr < NGRP; ++gr) {
            const int k  = gr * 4 + q;
            const int ks = (k < NK) ? k : (NK - 1);       // dup rows write same data: benign
            *reinterpret_cast<float4*>(sit + ks * NH + ((l16 ^ (ks & 15)) << 2)) = r[gr];
        }
        sue[lane] = uev;

        // ---- user norm (uses current uev before it is overwritten) ----
        float us = uev * uev;
        #pragma unroll
        for (int off = 32; off > 0; off >>= 1) us += __shfl_down(us, off);
        if (lane == 0) uen_acc += sqrtf(us);

        const float ibv_c = ibv, tgt_c = tgt;             // keep current-g copies

        // ---- prefetch next-g operands and issue next rows (overlap consume) ----
        if (g + 1 < G) {
            u    = user[b + 1];
            kidx = item[(b + 1) * NK + kcl];
            ubv  = user_bias[u];
            tgt  = target[(b + 1) * NK + kcl];
            ibv  = item_bias[kidx];
            uev  = user_weight[(size_t)u * NH + lane] + ubv;
            #pragma unroll
            for (int gr = 0; gr < NGRP; ++gr) {
                const int k  = gr * 4 + q;
                const int kk = (k < NK) ? k : (NK - 1);
                const int it = __shfl(kidx, kk);
                r[gr] = *reinterpret_cast<const float4*>(item_weight + (size_t)it * NH + l16 * 4);
            }
        }

        // ---- consume: lane k dots row k fully in-lane ----
        const int ksw = kcl & 15;
        const float* rowbase = sit + kcl * NH;
        float dot = 0.f, sq = 0.f;
        #pragma unroll
        for (int j = 0; j < 16; ++j) {
            const float4 iv = *reinterpret_cast<const float4*>(rowbase + ((j ^ ksw) << 2));
            const float4 uv = *reinterpret_cast<const float4*>(sue + (j << 2)); // broadcast
            const float iex = iv.x + ibv_c;
            const float iey = iv.y + ibv_c;
            const float iez = iv.z + ibv_c;
            const float iew = iv.w + ibv_c;
            dot += iex * uv.x + iey * uv.y + iez * uv.z + iew * uv.w;
            sq  += iex * iex  + iey * iey  + iez * iez  + iew * iew;
        }
        const float pred = dot + gb;
        if (active) {
            out[b * NK + lane] = pred;                    // coalesced 200B store
            const float d = pred - tgt_c;
            mse_acc += d * d;
            ien_acc += sqrtf(sq);
        }
        b += 1;
    }

    // ---- one wave reduction at the end ----
    #pragma unroll
    for (int off = 32; off > 0; off >>= 1) {
        mse_acc += __shfl_down(mse_acc, off);
        ien_acc += __shfl_down(ien_acc, off);
    }
    if (lane == 0) {
        s_red[0][wave] = mse_acc;
        s_red[1][wave] = uen_acc;
        s_red[2][wave] = ien_acc;
    }
    __syncthreads();
    if (tid == 0) {
        atomicAdd(&acc[0], s_red[0][0] + s_red[0][1] + s_red[0][2] + s_red[0][3]);
        atomicAdd(&acc[1], s_red[1][0] + s_red[1][1] + s_red[1][2] + s_red[1][3]);
        atomicAdd(&acc[2], s_red[2][0] + s_red[2][1] + s_red[2][2] + s_red[2][3]);
    }
}

__global__ void mf_finish(const float* __restrict__ acc, float* __restrict__ out)
{
    const float inv_bk = 1.0f / (float)(NB * NK);
    const float mse = acc[0] * inv_bk;
    const float loss = mse + REG * (acc[1] / (float)NB) + REG * (acc[2] * inv_bk);
    out[NB * NK] = loss;
}

extern "C" void kernel_launch(void* const* d_in, const int* in_sizes, int n_in,
                              void* d_out, int out_size, void* d_ws, size_t ws_size,
                              hipStream_t stream) {
    const float* user_weight = (const float*)d_in[0];
    const float* item_weight = (const float*)d_in[1];
    const float* user_bias   = (const float*)d_in[2];
    const float* item_bias   = (const float*)d_in[3];
    const float* gbias       = (const float*)d_in[4];
    const float* target      = (const float*)d_in[5];
    const int*   user        = (const int*)d_in[6];
    const int*   item        = (const int*)d_in[7];
    float* out = (float*)d_out;
    float* acc = (float*)d_ws;

    hipMemsetAsync(acc, 0, 3 * sizeof(float), stream);
    mf_main<<<NB / (4 * G), 256, 0, stream>>>(user_weight, item_weight, user_bias, item_bias,
                                              gbias, target, user, item, out, acc);
    mf_finish<<<1, 1, 0, stream>>>(acc, out);
}